// Round 4
// baseline (628.996 us; speedup 1.0000x reference)
//
#include <hip/hip_runtime.h>

typedef unsigned short u16;
typedef unsigned int   u32;
typedef unsigned long long u64;

typedef __attribute__((ext_vector_type(8))) __bf16 bf16x8;
typedef __attribute__((ext_vector_type(4))) float  floatx4;

#define D_MODEL 1024
#define L_SEQ   4096
#define BATCH   4
#define N_HEADS 16
#define D_HEAD  64
#define CHUNK   128
#define N_CHUNKS 32
#define M_ROWS  (BATCH * L_SEQ)   // 16384

// ---------- bf16 helpers (manual, exact widening / RNE narrowing) ----------
__device__ __forceinline__ float bf2f(u16 u) {
    union { u32 i; float f; } x; x.i = ((u32)u) << 16; return x.f;
}
__device__ __forceinline__ float bflo(u32 u) {
    union { u32 i; float f; } x; x.i = u << 16; return x.f;
}
__device__ __forceinline__ float bfhi(u32 u) {
    union { u32 i; float f; } x; x.i = u & 0xFFFF0000u; return x.f;
}
__device__ __forceinline__ u16 f2bf(float f) {
    union { u32 i; float fl; } x; x.fl = f;
    u32 i = x.i;
    u32 r = (i + 0x7FFFu + ((i >> 16) & 1u)) >> 16;
    return (u16)r;
}

// decay may be fp32 or bf16; detect from element 0 read as bf16.
// fp32 0.9 -> low u16 0x6666 -> bf16 = 2.7e23 (insane) -> fp32 path.
__device__ __forceinline__ float load_decay(const void* dec, int h) {
    const u16* d16 = (const u16*)dec;
    const float as_bf = bf2f(d16[0]);
    if (as_bf > 1e-6f && as_bf <= 1.0001f) return bf2f(d16[h]);
    return ((const float*)dec)[h];
}

// ---------- dtype detection: flags[0]=x is fp32, flags[1]=W is fp32 --------
__global__ void detect_dtypes(const void* __restrict__ x,
                              const void* __restrict__ w,
                              int* __restrict__ flags) {
    const int lane = threadIdx.x;                 // 64 threads
    const u16* x16 = (const u16*)x;
    const u16* w16 = (const u16*)w;
    const float vx = fabsf(bf2f(x16[lane]));
    const float vw = fabsf(bf2f(w16[lane]));
    const bool ox = (vx != 0.0f) && (vx > 1e4f || vx < 1e-4f);
    const bool ow = (vw != 0.0f) && (vw > 1e4f || vw < 1e-4f);
    const u64 bx = __ballot(ox);
    const u64 bw = __ballot(ow);
    if (lane == 0) {
        flags[0] = (__popcll(bx) >= 8) ? 1 : 0;
        flags[1] = (__popcll(bw) >= 8) ? 1 : 0;
    }
}

// ---------- x -> canonical bf16 buffer ----------
__global__ __launch_bounds__(256)
void convert_x(const void* __restrict__ x, const int* __restrict__ flags,
               u16* __restrict__ xb) {
    const int mode = flags[0];
    const size_t i0 = ((size_t)blockIdx.x * 256 + threadIdx.x) * 8;
    if (mode) {
        const float* xf = (const float*)x;
        u16 tmp[8];
#pragma unroll
        for (int j = 0; j < 8; j++) tmp[j] = f2bf(xf[i0 + j]);
        *(uint4*)(xb + i0) = *(const uint4*)tmp;
    } else {
        *(uint4*)(xb + i0) = *(const uint4*)((const u16*)x + i0);
    }
}

// ---------- weight transpose: T[n][k] = bf16(W[k][n]), dual dtype ----------
__global__ __launch_bounds__(256)
void transpose4(const void* __restrict__ W0, const void* __restrict__ W1,
                const void* __restrict__ W2, const void* __restrict__ W3,
                const int* __restrict__ flags,
                u16* __restrict__ T0, u16* __restrict__ T1,
                u16* __restrict__ T2, u16* __restrict__ T3) {
    __shared__ u16 tile[32][33];
    const int mode = flags[1];
    const void* src; u16* dst;
    switch (blockIdx.z) {
        case 0: src = W0; dst = T0; break;
        case 1: src = W1; dst = T1; break;
        case 2: src = W2; dst = T2; break;
        default: src = W3; dst = T3; break;
    }
    const int tx = threadIdx.x & 31, ty = threadIdx.x >> 5;  // ty in 0..7
    const int x0 = blockIdx.x * 32, y0 = blockIdx.y * 32;
#pragma unroll
    for (int i = 0; i < 32; i += 8) {
        const size_t idx = (size_t)(y0 + ty + i) * D_MODEL + x0 + tx;
        tile[ty + i][tx] = mode ? f2bf(((const float*)src)[idx])
                                : ((const u16*)src)[idx];
    }
    __syncthreads();
#pragma unroll
    for (int i = 0; i < 32; i += 8)
        dst[(size_t)(x0 + ty + i) * D_MODEL + y0 + tx] = tile[tx][ty + i];
}

// ---------- GEMM: C[m][n] = OutT( sum_k A[m][k] * Bt[n][k] + bias[n] ) -----
// A: [M,K] bf16 row-major.  Bt: [N,K] bf16 row-major (pre-transposed weight).
// OutT = u16 (bf16 store, intermediates) or float (fp32 store, final output).
#define BK 32
#define SA 40   // LDS row stride (elems): 32 + 8 pad, keeps 16B alignment

template <typename OutT>
__global__ __launch_bounds__(256)
void gemm_bt_bias(const u16* __restrict__ A, const u16* __restrict__ Bt,
                  const u16* __restrict__ bias, OutT* __restrict__ C,
                  int M, int N, int K) {
    __shared__ u16 As[128 * SA];
    __shared__ u16 Bs[128 * SA];
    const int t    = threadIdx.x;
    const int lane = t & 63;
    const int wave = t >> 6;
    const int wm   = wave >> 1;       // 0..1
    const int wn   = wave & 1;        // 0..1
    const int col  = lane & 15;
    const int quad = lane >> 4;
    const int m0 = blockIdx.y * 128;
    const int n0 = blockIdx.x * 128;

    const int lrow = t >> 2;          // 0..63
    const int lkc  = (t & 3) << 3;    // 0,8,16,24

    floatx4 acc[4][4];
#pragma unroll
    for (int i = 0; i < 4; i++)
#pragma unroll
        for (int j = 0; j < 4; j++)
            acc[i][j] = floatx4{0.f, 0.f, 0.f, 0.f};

    const u16* Ap0 = A  + (size_t)(m0 + lrow) * K + lkc;
    const u16* Ap1 = A  + (size_t)(m0 + lrow + 64) * K + lkc;
    const u16* Bp0 = Bt + (size_t)(n0 + lrow) * K + lkc;
    const u16* Bp1 = Bt + (size_t)(n0 + lrow + 64) * K + lkc;

    for (int k0 = 0; k0 < K; k0 += BK) {
        uint4 a0 = *(const uint4*)(Ap0 + k0);
        uint4 a1 = *(const uint4*)(Ap1 + k0);
        uint4 b0 = *(const uint4*)(Bp0 + k0);
        uint4 b1 = *(const uint4*)(Bp1 + k0);
        __syncthreads();   // prior iteration's frag reads done
        *(uint4*)(&As[lrow * SA + lkc])        = a0;
        *(uint4*)(&As[(lrow + 64) * SA + lkc]) = a1;
        *(uint4*)(&Bs[lrow * SA + lkc])        = b0;
        *(uint4*)(&Bs[(lrow + 64) * SA + lkc]) = b1;
        __syncthreads();

        bf16x8 af[4], bfr[4];
#pragma unroll
        for (int i = 0; i < 4; i++)
            af[i] = *(const bf16x8*)(&As[(wm * 64 + i * 16 + col) * SA + quad * 8]);
#pragma unroll
        for (int j = 0; j < 4; j++)
            bfr[j] = *(const bf16x8*)(&Bs[(wn * 64 + j * 16 + col) * SA + quad * 8]);
#pragma unroll
        for (int i = 0; i < 4; i++)
#pragma unroll
            for (int j = 0; j < 4; j++)
                acc[i][j] = __builtin_amdgcn_mfma_f32_16x16x32_bf16(
                    af[i], bfr[j], acc[i][j], 0, 0, 0);
    }

    // epilogue: C/D layout col=lane&15, row=quad*4+reg
#pragma unroll
    for (int j = 0; j < 4; j++) {
        const int gc = n0 + wn * 64 + j * 16 + col;
        const float bsf = bf2f(bias[gc]);
#pragma unroll
        for (int i = 0; i < 4; i++) {
            const int gr = m0 + wm * 64 + i * 16 + quad * 4;
#pragma unroll
            for (int r = 0; r < 4; r++) {
                const float val = acc[i][j][r] + bsf;
                if constexpr (sizeof(OutT) == 2)
                    C[(size_t)(gr + r) * N + gc] = (OutT)f2bf(val);
                else
                    C[(size_t)(gr + r) * N + gc] = (OutT)val;
            }
        }
    }
}

// ---------- retention: per (chunk, b, h) tile, flash-style softmax ---------
__global__ __launch_bounds__(256)
void retention_k(const u16* __restrict__ q, const u16* __restrict__ k,
                 const u16* __restrict__ v, const void* __restrict__ dec,
                 u16* __restrict__ att) {
    __shared__ float ks[129 * 64];   // f32 keys
    __shared__ u16   vs[129 * 64];   // bf16 values
    const int c = blockIdx.x, b = blockIdx.y, h = blockIdx.z;
    const int t = threadIdx.x;
    const size_t base = ((size_t)b * L_SEQ) * D_MODEL + h * D_HEAD;

    // stage kf/vf: j=0 is global position c*128-1 (zeros for chunk 0)
    for (int idx = t; idx < 129 * 64; idx += 256) {
        const int j = idx >> 6, d = idx & 63;
        const int gl = c * CHUNK + j - 1;
        float kv = 0.f; u16 vv = 0;
        if (gl >= 0) {
            const size_t off = base + (size_t)gl * D_MODEL + d;
            kv = bf2f(k[off]);
            vv = v[off];
        }
        ks[idx] = kv;
        vs[idx] = vv;
    }

    // thread pair (r, half): lanes 2r and 2r+1 split the 64-d dimension
    const int r = t >> 1;
    const int half = t & 1;
    const float dval = load_decay(dec, h);
    // dp = decay^r * Dh^-0.5 (dval in (0,1], r<=127)
    const float dp = __expf((float)r * __logf(dval)) * 0.125f;

    float qreg[32];
    {
        const u16* qp = q + base + (size_t)(c * CHUNK + r) * D_MODEL + half * 32;
#pragma unroll
        for (int g = 0; g < 4; g++) {
            uint4 uu = *(const uint4*)(qp + g * 8);
            qreg[g*8+0] = bflo(uu.x) * dp; qreg[g*8+1] = bfhi(uu.x) * dp;
            qreg[g*8+2] = bflo(uu.y) * dp; qreg[g*8+3] = bfhi(uu.y) * dp;
            qreg[g*8+4] = bflo(uu.z) * dp; qreg[g*8+5] = bfhi(uu.z) * dp;
            qreg[g*8+6] = bflo(uu.w) * dp; qreg[g*8+7] = bfhi(uu.w) * dp;
        }
    }
    __syncthreads();

    float mval = -1.0e30f, l = 0.f;
    float acc[32];
#pragma unroll
    for (int d = 0; d < 32; d++) acc[d] = 0.f;

    for (int j = 0; j < 129; j++) {
        const float* kr = &ks[j * 64 + half * 32];
        float p0 = 0.f, p1 = 0.f, p2 = 0.f, p3 = 0.f;
#pragma unroll
        for (int d = 0; d < 32; d += 4) {
            p0 += qreg[d]     * kr[d];
            p1 += qreg[d + 1] * kr[d + 1];
            p2 += qreg[d + 2] * kr[d + 2];
            p3 += qreg[d + 3] * kr[d + 3];
        }
        float s = (p0 + p1) + (p2 + p3);
        s += __shfl_xor(s, 1, 64);          // combine the two d-halves
        if (s > mval) {                      // online softmax rescale
            const float fac = __expf(fmaxf(mval - s, -80.f));
            l *= fac;
#pragma unroll
            for (int d = 0; d < 32; d++) acc[d] *= fac;
            mval = s;
        }
        const float w = __expf(s - mval);   // in (0,1]
        l += w;
        const u32* vr = (const u32*)(&vs[j * 64 + half * 32]);
#pragma unroll
        for (int d = 0; d < 16; d++) {
            const u32 uu = vr[d];
            acc[2*d]     += w * bflo(uu);
            acc[2*d + 1] += w * bfhi(uu);
        }
    }
    const float inv = 1.f / l;
    u16* op = att + base + (size_t)(c * CHUNK + r) * D_MODEL + half * 32;
#pragma unroll
    for (int d = 0; d < 32; d++) op[d] = f2bf(acc[d] * inv);
}

// ---------------------------- launcher -------------------------------------
extern "C" void kernel_launch(void* const* d_in, const int* in_sizes, int n_in,
                              void* d_out, int out_size, void* d_ws, size_t ws_size,
                              hipStream_t stream) {
    const void* x   = d_in[0];
    const void* Wq  = d_in[1];
    const u16*  bq  = (const u16*)d_in[2];
    const void* Wk  = d_in[3];
    const u16*  bk  = (const u16*)d_in[4];
    const void* Wv  = d_in[5];
    const u16*  bv  = (const u16*)d_in[6];
    const void* Wo  = d_in[7];
    const u16*  bo  = (const u16*)d_in[8];
    const void* dec = d_in[9];
    float* out = (float*)d_out;               // reference output dtype: fp32

    char* ws = (char*)d_ws;
    const size_t mat = (size_t)M_ROWS * D_MODEL * sizeof(u16);   // 33.5 MB
    const size_t wsz = (size_t)D_MODEL * D_MODEL * sizeof(u16);  // 2 MB
    u16* xb  = (u16*)(ws);                    // canonical bf16 x; later: att
    u16* qb  = (u16*)(ws + mat);
    u16* kb  = (u16*)(ws + 2 * mat);
    u16* vb  = (u16*)(ws + 3 * mat);
    u16* WqT = (u16*)(ws + 4 * mat);
    u16* WkT = (u16*)(ws + 4 * mat + wsz);
    u16* WvT = (u16*)(ws + 4 * mat + 2 * wsz);
    u16* WoT = (u16*)(ws + 4 * mat + 3 * wsz);
    int* flags = (int*)(ws + 4 * mat + 4 * wsz);

    dim3 tb(256);
    detect_dtypes<<<1, 64, 0, stream>>>(x, Wq, flags);
    convert_x<<<8192, tb, 0, stream>>>(x, flags, xb);
    transpose4<<<dim3(32, 32, 4), tb, 0, stream>>>(Wq, Wk, Wv, Wo, flags,
                                                   WqT, WkT, WvT, WoT);
    gemm_bt_bias<u16><<<dim3(8, 128), tb, 0, stream>>>(xb, WqT, bq, qb,
                                                       M_ROWS, D_MODEL, D_MODEL);
    gemm_bt_bias<u16><<<dim3(8, 128), tb, 0, stream>>>(xb, WkT, bk, kb,
                                                       M_ROWS, D_MODEL, D_MODEL);
    gemm_bt_bias<u16><<<dim3(8, 128), tb, 0, stream>>>(xb, WvT, bv, vb,
                                                       M_ROWS, D_MODEL, D_MODEL);
    // retention reads qb/kb/vb, writes att over xb (x is dead here)
    retention_k<<<dim3(N_CHUNKS, BATCH, N_HEADS), tb, 0, stream>>>(qb, kb, vb,
                                                                   dec, xb);
    gemm_bt_bias<float><<<dim3(8, 128), tb, 0, stream>>>(xb, WoT, bo, out,
                                                         M_ROWS, D_MODEL, D_MODEL);
}

// Round 5
// 439.940 us; speedup vs baseline: 1.4297x; 1.4297x over previous
//
#include <hip/hip_runtime.h>

typedef unsigned short u16;
typedef unsigned int   u32;
typedef unsigned long long u64;

typedef __attribute__((ext_vector_type(8))) __bf16 bf16x8;
typedef __attribute__((ext_vector_type(4))) float  floatx4;

#define D_MODEL 1024
#define L_SEQ   4096
#define BATCH   4
#define N_HEADS 16
#define D_HEAD  64
#define CHUNK   128
#define N_CHUNKS 32
#define M_ROWS  (BATCH * L_SEQ)   // 16384

// ---------- bf16 helpers (manual, exact widening / RNE narrowing) ----------
__device__ __forceinline__ float bf2f(u16 u) {
    union { u32 i; float f; } x; x.i = ((u32)u) << 16; return x.f;
}
__device__ __forceinline__ u16 f2bf(float f) {
    union { u32 i; float fl; } x; x.fl = f;
    u32 i = x.i;
    u32 r = (i + 0x7FFFu + ((i >> 16) & 1u)) >> 16;
    return (u16)r;
}

// decay may be fp32 or bf16; detect from element 0 read as bf16.
__device__ __forceinline__ float load_decay(const void* dec, int h) {
    const u16* d16 = (const u16*)dec;
    const float as_bf = bf2f(d16[0]);
    if (as_bf > 1e-6f && as_bf <= 1.0001f) return bf2f(d16[h]);
    return ((const float*)dec)[h];
}

// ---------- dtype detection: flags[0]=x is fp32, flags[1]=W is fp32 --------
__global__ void detect_dtypes(const void* __restrict__ x,
                              const void* __restrict__ w,
                              int* __restrict__ flags) {
    const int lane = threadIdx.x;                 // 64 threads
    const u16* x16 = (const u16*)x;
    const u16* w16 = (const u16*)w;
    const float vx = fabsf(bf2f(x16[lane]));
    const float vw = fabsf(bf2f(w16[lane]));
    const bool ox = (vx != 0.0f) && (vx > 1e4f || vx < 1e-4f);
    const bool ow = (vw != 0.0f) && (vw > 1e4f || vw < 1e-4f);
    const u64 bx = __ballot(ox);
    const u64 bw = __ballot(ow);
    if (lane == 0) {
        flags[0] = (__popcll(bx) >= 8) ? 1 : 0;
        flags[1] = (__popcll(bw) >= 8) ? 1 : 0;
    }
}

// ---------- x -> canonical bf16 buffer ----------
__global__ __launch_bounds__(256)
void convert_x(const void* __restrict__ x, const int* __restrict__ flags,
               u16* __restrict__ xb) {
    const int mode = flags[0];
    const size_t i0 = ((size_t)blockIdx.x * 256 + threadIdx.x) * 8;
    if (mode) {
        const float* xf = (const float*)x;
        u16 tmp[8];
#pragma unroll
        for (int j = 0; j < 8; j++) tmp[j] = f2bf(xf[i0 + j]);
        *(uint4*)(xb + i0) = *(const uint4*)tmp;
    } else {
        *(uint4*)(xb + i0) = *(const uint4*)((const u16*)x + i0);
    }
}

// ---------- weight transpose: T[n][k] = bf16(W[k][n]), dual dtype ----------
__global__ __launch_bounds__(256)
void transpose4(const void* __restrict__ W0, const void* __restrict__ W1,
                const void* __restrict__ W2, const void* __restrict__ W3,
                const int* __restrict__ flags,
                u16* __restrict__ T0, u16* __restrict__ T1,
                u16* __restrict__ T2, u16* __restrict__ T3) {
    __shared__ u16 tile[32][33];
    const int mode = flags[1];
    const void* src; u16* dst;
    switch (blockIdx.z) {
        case 0: src = W0; dst = T0; break;
        case 1: src = W1; dst = T1; break;
        case 2: src = W2; dst = T2; break;
        default: src = W3; dst = T3; break;
    }
    const int tx = threadIdx.x & 31, ty = threadIdx.x >> 5;  // ty in 0..7
    const int x0 = blockIdx.x * 32, y0 = blockIdx.y * 32;
#pragma unroll
    for (int i = 0; i < 32; i += 8) {
        const size_t idx = (size_t)(y0 + ty + i) * D_MODEL + x0 + tx;
        tile[ty + i][tx] = mode ? f2bf(((const float*)src)[idx])
                                : ((const u16*)src)[idx];
    }
    __syncthreads();
#pragma unroll
    for (int i = 0; i < 32; i += 8)
        dst[(size_t)(x0 + ty + i) * D_MODEL + y0 + tx] = tile[tx][ty + i];
}

// ---------- GEMM: C[m][n] = OutT( sum_k A[m][k] * Bt[n][k] + bias[n] ) -----
#define BK 32
#define SA 40   // LDS row stride (elems): 32 + 8 pad, keeps 16B alignment

template <typename OutT>
__global__ __launch_bounds__(256)
void gemm_bt_bias(const u16* __restrict__ A, const u16* __restrict__ Bt,
                  const u16* __restrict__ bias, OutT* __restrict__ C,
                  int M, int N, int K) {
    __shared__ u16 As[128 * SA];
    __shared__ u16 Bs[128 * SA];
    const int t    = threadIdx.x;
    const int lane = t & 63;
    const int wave = t >> 6;
    const int wm   = wave >> 1;       // 0..1
    const int wn   = wave & 1;        // 0..1
    const int col  = lane & 15;
    const int quad = lane >> 4;
    const int m0 = blockIdx.y * 128;
    const int n0 = blockIdx.x * 128;

    const int lrow = t >> 2;          // 0..63
    const int lkc  = (t & 3) << 3;    // 0,8,16,24

    floatx4 acc[4][4];
#pragma unroll
    for (int i = 0; i < 4; i++)
#pragma unroll
        for (int j = 0; j < 4; j++)
            acc[i][j] = floatx4{0.f, 0.f, 0.f, 0.f};

    const u16* Ap0 = A  + (size_t)(m0 + lrow) * K + lkc;
    const u16* Ap1 = A  + (size_t)(m0 + lrow + 64) * K + lkc;
    const u16* Bp0 = Bt + (size_t)(n0 + lrow) * K + lkc;
    const u16* Bp1 = Bt + (size_t)(n0 + lrow + 64) * K + lkc;

    for (int k0 = 0; k0 < K; k0 += BK) {
        uint4 a0 = *(const uint4*)(Ap0 + k0);
        uint4 a1 = *(const uint4*)(Ap1 + k0);
        uint4 b0 = *(const uint4*)(Bp0 + k0);
        uint4 b1 = *(const uint4*)(Bp1 + k0);
        __syncthreads();   // prior iteration's frag reads done
        *(uint4*)(&As[lrow * SA + lkc])        = a0;
        *(uint4*)(&As[(lrow + 64) * SA + lkc]) = a1;
        *(uint4*)(&Bs[lrow * SA + lkc])        = b0;
        *(uint4*)(&Bs[(lrow + 64) * SA + lkc]) = b1;
        __syncthreads();

        bf16x8 af[4], bfr[4];
#pragma unroll
        for (int i = 0; i < 4; i++)
            af[i] = *(const bf16x8*)(&As[(wm * 64 + i * 16 + col) * SA + quad * 8]);
#pragma unroll
        for (int j = 0; j < 4; j++)
            bfr[j] = *(const bf16x8*)(&Bs[(wn * 64 + j * 16 + col) * SA + quad * 8]);
#pragma unroll
        for (int i = 0; i < 4; i++)
#pragma unroll
            for (int j = 0; j < 4; j++)
                acc[i][j] = __builtin_amdgcn_mfma_f32_16x16x32_bf16(
                    af[i], bfr[j], acc[i][j], 0, 0, 0);
    }

    // epilogue: C/D layout col=lane&15, row=quad*4+reg
#pragma unroll
    for (int j = 0; j < 4; j++) {
        const int gc = n0 + wn * 64 + j * 16 + col;
        const float bsf = bf2f(bias[gc]);
#pragma unroll
        for (int i = 0; i < 4; i++) {
            const int gr = m0 + wm * 64 + i * 16 + quad * 4;
#pragma unroll
            for (int r = 0; r < 4; r++) {
                const float val = acc[i][j][r] + bsf;
                if constexpr (sizeof(OutT) == 2)
                    C[(size_t)(gr + r) * N + gc] = (OutT)f2bf(val);
                else
                    C[(size_t)(gr + r) * N + gc] = (OutT)val;
            }
        }
    }
}

// ---------- retention via MFMA: one block per (chunk, b, h) tile -----------
// S = (Q*dp_row) . Kf^T (129 keys: carry + 128), softmax rows, O = P . Vf.
// In-chunk 128 keys via MFMA; carry key handled as a rank-1 VALU term.
#define QS 72    // Qs/Ks row stride (64 + 8): rows 4 banks apart, 16B aligned
#define PS 136   // Ps row stride (128 + 8): 16B aligned, rows 4 banks apart
#define VT 136   // Vt row stride (128 + 8)
#define KS_OFF (128 * QS)

__global__ __launch_bounds__(256)
void retention_mfma(const u16* __restrict__ q, const u16* __restrict__ k,
                    const u16* __restrict__ v, const void* __restrict__ dec,
                    u16* __restrict__ att) {
    __shared__ u16 qk[2 * 128 * QS];   // Qs | Ks ; later overlaid by Ps
    __shared__ u16 vt[64 * VT];        // V^T: [d][key]
    __shared__ float kp[64], vp[64], s0f[128];
    u16* Ps = qk;                      // 128*PS = 17408 <= 18432 ok

    const int c = blockIdx.x, b = blockIdx.y, h = blockIdx.z;
    const int t = threadIdx.x;
    const int lane = t & 63, w = t >> 6;
    const int col16 = lane & 15, quad = lane >> 4;
    const int R0 = w * 32;
    const size_t base = ((size_t)b * L_SEQ) * D_MODEL + h * D_HEAD;
    const size_t gbase = base + (size_t)(c * CHUNK) * D_MODEL;

    // ---- stage Q, K (row-major) and V (transposed) ----
#pragma unroll
    for (int it = 0; it < 4; it++) {
        const int i = it * 256 + t;
        const int row = i >> 3, seg = i & 7;
        const size_t go = gbase + (size_t)row * D_MODEL + seg * 8;
        *(uint4*)&qk[row * QS + seg * 8]          = *(const uint4*)(q + go);
        *(uint4*)&qk[KS_OFF + row * QS + seg * 8] = *(const uint4*)(k + go);
    }
#pragma unroll
    for (int it = 0; it < 4; it++) {
        const int i = it * 256 + t;
        const int key = i & 127, dseg = i >> 7;
        u16 tmp[8];
        *(uint4*)tmp = *(const uint4*)(v + gbase + (size_t)key * D_MODEL + dseg * 8);
#pragma unroll
        for (int j = 0; j < 8; j++)
            vt[(dseg * 8 + j) * VT + key] = tmp[j];
    }
    if (t < 64) {
        const int gl = c * CHUNK - 1;
        float kpv = 0.f, vpv = 0.f;
        if (gl >= 0) {
            const size_t go = base + (size_t)gl * D_MODEL + t;
            kpv = bf2f(k[go]);
            vpv = bf2f(v[go]);
        }
        kp[t] = kpv; vp[t] = vpv;
    }
    __syncthreads();

    // ---- carry scores s0[row] = q_row . k_prev (2 threads per row) ----
    {
        const int row = t >> 1, half = t & 1;
        const u16* qrow = &qk[row * QS + half * 32];
        float s = 0.f;
#pragma unroll
        for (int d = 0; d < 32; d++) s += bf2f(qrow[d]) * kp[half * 32 + d];
        s += __shfl_xor(s, 1, 64);
        if (half == 0) s0f[row] = s;
    }
    __syncthreads();

    // ---- S-MFMA: wave w computes rows R0..R0+32 x all 128 keys ----
    floatx4 accs[2][8];
#pragma unroll
    for (int rt = 0; rt < 2; rt++)
#pragma unroll
        for (int ct = 0; ct < 8; ct++)
            accs[rt][ct] = floatx4{0.f, 0.f, 0.f, 0.f};

#pragma unroll
    for (int k0 = 0; k0 < 2; k0++) {
        bf16x8 af0 = *(const bf16x8*)&qk[(R0 + col16) * QS + k0 * 32 + quad * 8];
        bf16x8 af1 = *(const bf16x8*)&qk[(R0 + 16 + col16) * QS + k0 * 32 + quad * 8];
#pragma unroll
        for (int ct = 0; ct < 8; ct++) {
            bf16x8 bfr = *(const bf16x8*)&qk[KS_OFF + (ct * 16 + col16) * QS + k0 * 32 + quad * 8];
            accs[0][ct] = __builtin_amdgcn_mfma_f32_16x16x32_bf16(af0, bfr, accs[0][ct], 0, 0, 0);
            accs[1][ct] = __builtin_amdgcn_mfma_f32_16x16x32_bf16(af1, bfr, accs[1][ct], 0, 0, 0);
        }
    }
    __syncthreads();   // all waves done reading qk before Ps overlay

    // ---- softmax per row in-register; write unnormalized P (bf16) ----
    const float dval = load_decay(dec, h);
    const float logd = __logf(dval);
    float p0v[2][4], invv[2][4];
#pragma unroll
    for (int rt = 0; rt < 2; rt++) {
#pragma unroll
        for (int r = 0; r < 4; r++) {
            const int row = R0 + rt * 16 + quad * 4 + r;
            const float dp = __expf((float)row * logd) * 0.125f;
            const float s0p = s0f[row] * dp;
            float vals[8];
            float vmax = s0p;
#pragma unroll
            for (int ct = 0; ct < 8; ct++) {
                vals[ct] = accs[rt][ct][r] * dp;
                vmax = fmaxf(vmax, vals[ct]);
            }
#pragma unroll
            for (int off = 1; off < 16; off <<= 1)
                vmax = fmaxf(vmax, __shfl_xor(vmax, off, 64));
            float lsum = 0.f;
#pragma unroll
            for (int ct = 0; ct < 8; ct++) {
                const float e = __expf(vals[ct] - vmax);
                lsum += e;
                Ps[row * PS + ct * 16 + col16] = f2bf(e);
            }
#pragma unroll
            for (int off = 1; off < 16; off <<= 1)
                lsum += __shfl_xor(lsum, off, 64);
            const float p0 = __expf(s0p - vmax);
            p0v[rt][r] = p0;
            invv[rt][r] = 1.0f / (lsum + p0);
        }
    }
    // no barrier needed: wave w only re-reads its own rows of Ps

    // ---- PV-MFMA: O[R0..R0+32][0..64] ----
    floatx4 acco[2][4];
#pragma unroll
    for (int rt = 0; rt < 2; rt++)
#pragma unroll
        for (int nt = 0; nt < 4; nt++)
            acco[rt][nt] = floatx4{0.f, 0.f, 0.f, 0.f};

#pragma unroll
    for (int k0 = 0; k0 < 4; k0++) {
        bf16x8 af0 = *(const bf16x8*)&Ps[(R0 + col16) * PS + k0 * 32 + quad * 8];
        bf16x8 af1 = *(const bf16x8*)&Ps[(R0 + 16 + col16) * PS + k0 * 32 + quad * 8];
#pragma unroll
        for (int nt = 0; nt < 4; nt++) {
            bf16x8 bfr = *(const bf16x8*)&vt[(nt * 16 + col16) * VT + k0 * 32 + quad * 8];
            acco[0][nt] = __builtin_amdgcn_mfma_f32_16x16x32_bf16(af0, bfr, acco[0][nt], 0, 0, 0);
            acco[1][nt] = __builtin_amdgcn_mfma_f32_16x16x32_bf16(af1, bfr, acco[1][nt], 0, 0, 0);
        }
    }

    // ---- epilogue: add carry rank-1 term, normalize, store bf16 ----
#pragma unroll
    for (int nt = 0; nt < 4; nt++) {
        const int gcol = nt * 16 + col16;
        const float vpc = vp[gcol];
#pragma unroll
        for (int rt = 0; rt < 2; rt++) {
#pragma unroll
            for (int r = 0; r < 4; r++) {
                const int row = R0 + rt * 16 + quad * 4 + r;
                const float val = (acco[rt][nt][r] + p0v[rt][r] * vpc) * invv[rt][r];
                att[gbase + (size_t)row * D_MODEL + gcol] = f2bf(val);
            }
        }
    }
}

// ---------------------------- launcher -------------------------------------
extern "C" void kernel_launch(void* const* d_in, const int* in_sizes, int n_in,
                              void* d_out, int out_size, void* d_ws, size_t ws_size,
                              hipStream_t stream) {
    const void* x   = d_in[0];
    const void* Wq  = d_in[1];
    const u16*  bq  = (const u16*)d_in[2];
    const void* Wk  = d_in[3];
    const u16*  bk  = (const u16*)d_in[4];
    const void* Wv  = d_in[5];
    const u16*  bv  = (const u16*)d_in[6];
    const void* Wo  = d_in[7];
    const u16*  bo  = (const u16*)d_in[8];
    const void* dec = d_in[9];
    float* out = (float*)d_out;               // reference output dtype: fp32

    char* ws = (char*)d_ws;
    const size_t mat = (size_t)M_ROWS * D_MODEL * sizeof(u16);   // 33.5 MB
    const size_t wsz = (size_t)D_MODEL * D_MODEL * sizeof(u16);  // 2 MB
    u16* xb  = (u16*)(ws);                    // canonical bf16 x; later: att
    u16* qb  = (u16*)(ws + mat);
    u16* kb  = (u16*)(ws + 2 * mat);
    u16* vb  = (u16*)(ws + 3 * mat);
    u16* WqT = (u16*)(ws + 4 * mat);
    u16* WkT = (u16*)(ws + 4 * mat + wsz);
    u16* WvT = (u16*)(ws + 4 * mat + 2 * wsz);
    u16* WoT = (u16*)(ws + 4 * mat + 3 * wsz);
    int* flags = (int*)(ws + 4 * mat + 4 * wsz);

    dim3 tb(256);
    detect_dtypes<<<1, 64, 0, stream>>>(x, Wq, flags);
    convert_x<<<8192, tb, 0, stream>>>(x, flags, xb);
    transpose4<<<dim3(32, 32, 4), tb, 0, stream>>>(Wq, Wk, Wv, Wo, flags,
                                                   WqT, WkT, WvT, WoT);
    gemm_bt_bias<u16><<<dim3(8, 128), tb, 0, stream>>>(xb, WqT, bq, qb,
                                                       M_ROWS, D_MODEL, D_MODEL);
    gemm_bt_bias<u16><<<dim3(8, 128), tb, 0, stream>>>(xb, WkT, bk, kb,
                                                       M_ROWS, D_MODEL, D_MODEL);
    gemm_bt_bias<u16><<<dim3(8, 128), tb, 0, stream>>>(xb, WvT, bv, vb,
                                                       M_ROWS, D_MODEL, D_MODEL);
    // retention reads qb/kb/vb, writes att over xb (x is dead here)
    retention_mfma<<<dim3(N_CHUNKS, BATCH, N_HEADS), tb, 0, stream>>>(qb, kb, vb,
                                                                      dec, xb);
    gemm_bt_bias<float><<<dim3(8, 128), tb, 0, stream>>>(xb, WoT, bo, out,
                                                         M_ROWS, D_MODEL, D_MODEL);
}

// Round 7
// 386.833 us; speedup vs baseline: 1.6260x; 1.1373x over previous
//
#include <hip/hip_runtime.h>

typedef unsigned short u16;
typedef unsigned int   u32;
typedef unsigned long long u64;

typedef __attribute__((ext_vector_type(8))) __bf16 bf16x8;
typedef __attribute__((ext_vector_type(4))) float  floatx4;

#define D_MODEL 1024
#define L_SEQ   4096
#define BATCH   4
#define N_HEADS 16
#define D_HEAD  64
#define CHUNK   128
#define N_CHUNKS 32
#define M_ROWS  (BATCH * L_SEQ)   // 16384
#define NQKV    3072              // fused q|k|v output width

// ---------- bf16 helpers ----------
__device__ __forceinline__ float bf2f(u16 u) {
    union { u32 i; float f; } x; x.i = ((u32)u) << 16; return x.f;
}
__device__ __forceinline__ u16 f2bf(float f) {
    union { u32 i; float fl; } x; x.fl = f;
    u32 i = x.i;
    u32 r = (i + 0x7FFFu + ((i >> 16) & 1u)) >> 16;
    return (u16)r;
}

__device__ __forceinline__ float load_decay(const void* dec, int h) {
    const u16* d16 = (const u16*)dec;
    const float as_bf = bf2f(d16[0]);
    if (as_bf > 1e-6f && as_bf <= 1.0001f) return bf2f(d16[h]);
    return ((const float*)dec)[h];
}

// direct global->LDS 16B async copy. HW semantics: per-lane global addr;
// LDS dest = wave-uniform base + lane*16 (m97/m104).
__device__ __forceinline__ void gload_lds16(const u16* g, u16* l) {
    __builtin_amdgcn_global_load_lds(
        (const __attribute__((address_space(1))) u32*)g,
        (__attribute__((address_space(3))) u32*)l, 16, 0, 0);
}

// ---------- dtype detection: flags[0]=x is fp32, flags[1]=W is fp32 --------
__global__ void detect_dtypes(const void* __restrict__ x,
                              const void* __restrict__ w,
                              int* __restrict__ flags) {
    const int lane = threadIdx.x;                 // 64 threads
    const u16* x16 = (const u16*)x;
    const u16* w16 = (const u16*)w;
    const float vx = fabsf(bf2f(x16[lane]));
    const float vw = fabsf(bf2f(w16[lane]));
    const bool ox = (vx != 0.0f) && (vx > 1e4f || vx < 1e-4f);
    const bool ow = (vw != 0.0f) && (vw > 1e4f || vw < 1e-4f);
    const u64 bx = __ballot(ox);
    const u64 bw = __ballot(ow);
    if (lane == 0) {
        flags[0] = (__popcll(bx) >= 8) ? 1 : 0;
        flags[1] = (__popcll(bw) >= 8) ? 1 : 0;
    }
}

// ---------- x -> canonical bf16 buffer ----------
__global__ __launch_bounds__(256)
void convert_x(const void* __restrict__ x, const int* __restrict__ flags,
               u16* __restrict__ xb) {
    const int mode = flags[0];
    const size_t i0 = ((size_t)blockIdx.x * 256 + threadIdx.x) * 8;
    if (mode) {
        const float* xf = (const float*)x;
        u16 tmp[8];
#pragma unroll
        for (int j = 0; j < 8; j++) tmp[j] = f2bf(xf[i0 + j]);
        *(uint4*)(xb + i0) = *(const uint4*)tmp;
    } else {
        *(uint4*)(xb + i0) = *(const uint4*)((const u16*)x + i0);
    }
}

// ---------- weight transpose: T[n][k] = bf16(W[k][n]), dual dtype ----------
__global__ __launch_bounds__(256)
void transpose4(const void* __restrict__ W0, const void* __restrict__ W1,
                const void* __restrict__ W2, const void* __restrict__ W3,
                const int* __restrict__ flags,
                u16* __restrict__ T0, u16* __restrict__ T1,
                u16* __restrict__ T2, u16* __restrict__ T3) {
    __shared__ u16 tile[32][33];
    const int mode = flags[1];
    const void* src; u16* dst;
    switch (blockIdx.z) {
        case 0: src = W0; dst = T0; break;
        case 1: src = W1; dst = T1; break;
        case 2: src = W2; dst = T2; break;
        default: src = W3; dst = T3; break;
    }
    const int tx = threadIdx.x & 31, ty = threadIdx.x >> 5;  // ty in 0..7
    const int x0 = blockIdx.x * 32, y0 = blockIdx.y * 32;
#pragma unroll
    for (int i = 0; i < 32; i += 8) {
        const size_t idx = (size_t)(y0 + ty + i) * D_MODEL + x0 + tx;
        tile[ty + i][tx] = mode ? f2bf(((const float*)src)[idx])
                                : ((const u16*)src)[idx];
    }
    __syncthreads();
#pragma unroll
    for (int i = 0; i < 32; i += 8)
        dst[(size_t)(x0 + ty + i) * D_MODEL + y0 + tx] = tile[tx][ty + i];
}

// ---------- bias concat: dst[0..4096) = bf16(bq|bk|bv|bo), dual dtype ------
__global__ __launch_bounds__(256)
void concat_bias(const void* __restrict__ bq, const void* __restrict__ bk,
                 const void* __restrict__ bv, const void* __restrict__ bo,
                 const int* __restrict__ flags, u16* __restrict__ dst) {
    const int i = blockIdx.x * 256 + threadIdx.x;  // 0..4095
    const int mode = flags[1];
    const int which = i >> 10, idx = i & 1023;
    const void* src = (which == 0) ? bq : (which == 1) ? bk
                      : (which == 2) ? bv : bo;
    dst[i] = mode ? f2bf(((const float*)src)[idx]) : ((const u16*)src)[idx];
}

// ---------- GEMM (m97 structure): C = A[16384,1024] . Bt[N,1024]^T + bias --
// global_load_lds 16B staging into unpadded LDS; XCD-aware block swizzle;
// u16 output goes through an LDS repack for coalesced 16B stores.
template <typename OutT>
__global__ __launch_bounds__(256)
void gemm_glds(const u16* __restrict__ A, const u16* __restrict__ Bt,
               const u16* __restrict__ bias, OutT* __restrict__ C, int N) {
    constexpr int K = 1024;
    __shared__ u16 sm[2 * 128 * 32];      // As | Bs (16 KB); reused by repack
    u16* As = sm;
    u16* Bs = sm + 128 * 32;

    const int t = threadIdx.x;
    const int lane = t & 63, w = t >> 6;
    const int col16 = lane & 15, quad = lane >> 4;
    const int wm = w >> 1, wn = w & 1;

    // swizzle: id%8 ~ XCD; each XCD owns 16 row-groups, col-tile outer
    const int id = blockIdx.x;
    const int xcd = id & 7;
    const int s = id >> 3;
    const int g = xcd * 16 + (s & 15);    // row group 0..127
    const int x = s >> 4;                 // col tile
    const int m0 = g * 128, n0 = x * 128;

    // staging addresses: wave w stages rows [w*16, w*16+16) and +64
    const int srow = lane >> 2;           // 0..15
    const int sseg = lane & 3;            // 16B segment
    const u16* Ab = A  + (size_t)(m0 + w * 16 + srow) * K + sseg * 8;
    const u16* Bb = Bt + (size_t)(n0 + w * 16 + srow) * K + sseg * 8;
    u16* AsW0 = &As[(w * 16) * 32];
    u16* AsW1 = &As[(w * 16 + 64) * 32];
    u16* BsW0 = &Bs[(w * 16) * 32];
    u16* BsW1 = &Bs[(w * 16 + 64) * 32];
    const size_t roff = (size_t)64 * K;

    floatx4 acc[4][4];
#pragma unroll
    for (int i = 0; i < 4; i++)
#pragma unroll
        for (int j = 0; j < 4; j++)
            acc[i][j] = floatx4{0.f, 0.f, 0.f, 0.f};

    for (int k0 = 0; k0 < K; k0 += 32) {
        __syncthreads();                  // prior frag reads done
        gload_lds16(Ab + k0, AsW0);
        gload_lds16(Ab + roff + k0, AsW1);
        gload_lds16(Bb + k0, BsW0);
        gload_lds16(Bb + roff + k0, BsW1);
        __syncthreads();                  // vmcnt(0) drain + barrier

        bf16x8 af[4], bfr[4];
#pragma unroll
        for (int i = 0; i < 4; i++)
            af[i] = *(const bf16x8*)(&As[(wm * 64 + i * 16 + col16) * 32 + quad * 8]);
#pragma unroll
        for (int j = 0; j < 4; j++)
            bfr[j] = *(const bf16x8*)(&Bs[(wn * 64 + j * 16 + col16) * 32 + quad * 8]);
#pragma unroll
        for (int i = 0; i < 4; i++)
#pragma unroll
            for (int j = 0; j < 4; j++)
                acc[i][j] = __builtin_amdgcn_mfma_f32_16x16x32_bf16(
                    af[i], bfr[j], acc[i][j], 0, 0, 0);
    }

    // epilogue. C/D layout: col=lane&15, row=quad*4+reg.
    if constexpr (sizeof(OutT) == 2) {
        // repack via LDS: 64 rows x 128 cols bf16 = 16 KB per pass
#pragma unroll
        for (int pass = 0; pass < 2; pass++) {
            __syncthreads();
            if (wm == pass) {
#pragma unroll
                for (int j = 0; j < 4; j++) {
                    const int lc = wn * 64 + j * 16 + col16;
                    const float bsf = bf2f(bias[n0 + lc]);
#pragma unroll
                    for (int i = 0; i < 4; i++)
#pragma unroll
                        for (int r = 0; r < 4; r++)
                            sm[(i * 16 + quad * 4 + r) * 128 + lc] =
                                f2bf(acc[i][j][r] + bsf);
                }
            }
            __syncthreads();
            // 64 rows x 16 uint4-segments per row = 1024 stores
#pragma unroll
            for (int it = 0; it < 4; it++) {
                const int lin = it * 256 + t;         // 0..1023
                const int row = lin >> 4, seg = lin & 15;   // FIXED indexing
                *(uint4*)&C[(size_t)(m0 + pass * 64 + row) * N + n0 + seg * 8] =
                    *(const uint4*)&sm[row * 128 + seg * 8];
            }
        }
    } else {
#pragma unroll
        for (int j = 0; j < 4; j++) {
            const int gc = n0 + wn * 64 + j * 16 + col16;
            const float bsf = bf2f(bias[gc]);
#pragma unroll
            for (int i = 0; i < 4; i++) {
                const int gr = m0 + wm * 64 + i * 16 + quad * 4;
#pragma unroll
                for (int r = 0; r < 4; r++)
                    C[(size_t)(gr + r) * N + gc] = acc[i][j][r] + bsf;
            }
        }
    }
}

// ---------- retention via MFMA: one block per (chunk, b, h) tile -----------
// Reads fused qkv [16384][3072] (q|k|v); writes att [16384][1024].
#define QS 72
#define PS 136
#define VT 136
#define KS_OFF (128 * QS)

__global__ __launch_bounds__(256)
void retention_mfma(const u16* __restrict__ qkv, const void* __restrict__ dec,
                    u16* __restrict__ att) {
    __shared__ u16 qk[2 * 128 * QS];   // Qs | Ks ; later overlaid by Ps
    __shared__ u16 vt[64 * VT];        // V^T: [d][key]
    __shared__ float kp[64], vp[64], s0f[128];
    u16* Ps = qk;

    const int c = blockIdx.x, b = blockIdx.y, h = blockIdx.z;
    const int t = threadIdx.x;
    const int lane = t & 63, w = t >> 6;
    const int col16 = lane & 15, quad = lane >> 4;
    const int R0 = w * 32;
    const size_t base  = ((size_t)b * L_SEQ) * NQKV + h * D_HEAD;
    const size_t gbase = base + (size_t)(c * CHUNK) * NQKV;
    const size_t obase = (((size_t)b * L_SEQ) + c * CHUNK) * D_MODEL + h * D_HEAD;

    // ---- stage Q, K (row-major) and V (transposed) ----
#pragma unroll
    for (int it = 0; it < 4; it++) {
        const int i = it * 256 + t;
        const int row = i >> 3, seg = i & 7;
        const size_t go = gbase + (size_t)row * NQKV + seg * 8;
        *(uint4*)&qk[row * QS + seg * 8]          = *(const uint4*)(qkv + go);
        *(uint4*)&qk[KS_OFF + row * QS + seg * 8] = *(const uint4*)(qkv + go + 1024);
    }
#pragma unroll
    for (int it = 0; it < 4; it++) {
        const int i = it * 256 + t;
        const int key = i & 127, dseg = i >> 7;
        u16 tmp[8];
        *(uint4*)tmp = *(const uint4*)(qkv + gbase + (size_t)key * NQKV + 2048 + dseg * 8);
#pragma unroll
        for (int j = 0; j < 8; j++)
            vt[(dseg * 8 + j) * VT + key] = tmp[j];
    }
    if (t < 64) {
        const int gl = c * CHUNK - 1;
        float kpv = 0.f, vpv = 0.f;
        if (gl >= 0) {
            const size_t go = base + (size_t)gl * NQKV + t;
            kpv = bf2f(qkv[go + 1024]);
            vpv = bf2f(qkv[go + 2048]);
        }
        kp[t] = kpv; vp[t] = vpv;
    }
    __syncthreads();

    // ---- carry scores s0[row] = q_row . k_prev (2 threads per row) ----
    {
        const int row = t >> 1, half = t & 1;
        const u16* qrow = &qk[row * QS + half * 32];
        float s = 0.f;
#pragma unroll
        for (int d = 0; d < 32; d++) s += bf2f(qrow[d]) * kp[half * 32 + d];
        s += __shfl_xor(s, 1, 64);
        if (half == 0) s0f[row] = s;
    }
    __syncthreads();

    // ---- S-MFMA: wave w computes rows R0..R0+32 x all 128 keys ----
    floatx4 accs[2][8];
#pragma unroll
    for (int rt = 0; rt < 2; rt++)
#pragma unroll
        for (int ct = 0; ct < 8; ct++)
            accs[rt][ct] = floatx4{0.f, 0.f, 0.f, 0.f};

#pragma unroll
    for (int k0 = 0; k0 < 2; k0++) {
        bf16x8 af0 = *(const bf16x8*)&qk[(R0 + col16) * QS + k0 * 32 + quad * 8];
        bf16x8 af1 = *(const bf16x8*)&qk[(R0 + 16 + col16) * QS + k0 * 32 + quad * 8];
#pragma unroll
        for (int ct = 0; ct < 8; ct++) {
            bf16x8 bfr = *(const bf16x8*)&qk[KS_OFF + (ct * 16 + col16) * QS + k0 * 32 + quad * 8];
            accs[0][ct] = __builtin_amdgcn_mfma_f32_16x16x32_bf16(af0, bfr, accs[0][ct], 0, 0, 0);
            accs[1][ct] = __builtin_amdgcn_mfma_f32_16x16x32_bf16(af1, bfr, accs[1][ct], 0, 0, 0);
        }
    }
    __syncthreads();   // all waves done reading qk before Ps overlay

    // ---- softmax per row in-register; write unnormalized P (bf16) ----
    const float dval = load_decay(dec, h);
    const float logd = __logf(dval);
    float p0v[2][4], invv[2][4];
#pragma unroll
    for (int rt = 0; rt < 2; rt++) {
#pragma unroll
        for (int r = 0; r < 4; r++) {
            const int row = R0 + rt * 16 + quad * 4 + r;
            const float dp = __expf((float)row * logd) * 0.125f;
            const float s0p = s0f[row] * dp;
            float vals[8];
            float vmax = s0p;
#pragma unroll
            for (int ct = 0; ct < 8; ct++) {
                vals[ct] = accs[rt][ct][r] * dp;
                vmax = fmaxf(vmax, vals[ct]);
            }
#pragma unroll
            for (int off = 1; off < 16; off <<= 1)
                vmax = fmaxf(vmax, __shfl_xor(vmax, off, 64));
            float lsum = 0.f;
#pragma unroll
            for (int ct = 0; ct < 8; ct++) {
                const float e = __expf(vals[ct] - vmax);
                lsum += e;
                Ps[row * PS + ct * 16 + col16] = f2bf(e);
            }
#pragma unroll
            for (int off = 1; off < 16; off <<= 1)
                lsum += __shfl_xor(lsum, off, 64);
            const float p0 = __expf(s0p - vmax);
            p0v[rt][r] = p0;
            invv[rt][r] = 1.0f / (lsum + p0);
        }
    }
    // no barrier needed: wave w only re-reads its own rows of Ps

    // ---- PV-MFMA: O[R0..R0+32][0..64] ----
    floatx4 acco[2][4];
#pragma unroll
    for (int rt = 0; rt < 2; rt++)
#pragma unroll
        for (int nt = 0; nt < 4; nt++)
            acco[rt][nt] = floatx4{0.f, 0.f, 0.f, 0.f};

#pragma unroll
    for (int k0 = 0; k0 < 4; k0++) {
        bf16x8 af0 = *(const bf16x8*)&Ps[(R0 + col16) * PS + k0 * 32 + quad * 8];
        bf16x8 af1 = *(const bf16x8*)&Ps[(R0 + 16 + col16) * PS + k0 * 32 + quad * 8];
#pragma unroll
        for (int nt = 0; nt < 4; nt++) {
            bf16x8 bfr = *(const bf16x8*)&vt[(nt * 16 + col16) * VT + k0 * 32 + quad * 8];
            acco[0][nt] = __builtin_amdgcn_mfma_f32_16x16x32_bf16(af0, bfr, acco[0][nt], 0, 0, 0);
            acco[1][nt] = __builtin_amdgcn_mfma_f32_16x16x32_bf16(af1, bfr, acco[1][nt], 0, 0, 0);
        }
    }

    // ---- epilogue: add carry rank-1 term, normalize, store bf16 ----
#pragma unroll
    for (int nt = 0; nt < 4; nt++) {
        const int gcol = nt * 16 + col16;
        const float vpc = vp[gcol];
#pragma unroll
        for (int rt = 0; rt < 2; rt++) {
#pragma unroll
            for (int r = 0; r < 4; r++) {
                const int row = R0 + rt * 16 + quad * 4 + r;
                const float val = (acco[rt][nt][r] + p0v[rt][r] * vpc) * invv[rt][r];
                att[obase + (size_t)row * D_MODEL + gcol] = f2bf(val);
            }
        }
    }
}

// ---------------------------- launcher -------------------------------------
extern "C" void kernel_launch(void* const* d_in, const int* in_sizes, int n_in,
                              void* d_out, int out_size, void* d_ws, size_t ws_size,
                              hipStream_t stream) {
    const void* x   = d_in[0];
    const void* Wq  = d_in[1];
    const void* bq  = d_in[2];
    const void* Wk  = d_in[3];
    const void* bk  = d_in[4];
    const void* Wv  = d_in[5];
    const void* bv  = d_in[6];
    const void* Wo  = d_in[7];
    const void* bo  = d_in[8];
    const void* dec = d_in[9];
    float* out = (float*)d_out;               // reference output dtype: fp32

    char* ws = (char*)d_ws;
    const size_t mat = (size_t)M_ROWS * D_MODEL * sizeof(u16);   // 33.5 MB
    const size_t wsz = (size_t)D_MODEL * D_MODEL * sizeof(u16);  // 2 MB
    u16* xb   = (u16*)(ws);                   // canonical bf16 x; later att
    u16* qkv  = (u16*)(ws + mat);             // fused [16384][3072]
    u16* WT   = (u16*)(ws + 4 * mat);         // WqT|WkT|WvT|WoT contiguous
    u16* WoT  = WT + 3 * (size_t)D_MODEL * D_MODEL;
    u16* bias = (u16*)(ws + 4 * mat + 4 * wsz);   // bq|bk|bv|bo bf16
    int* flags = (int*)(ws + 4 * mat + 4 * wsz + 8192);

    dim3 tb(256);
    detect_dtypes<<<1, 64, 0, stream>>>(x, Wq, flags);
    convert_x<<<8192, tb, 0, stream>>>(x, flags, xb);
    transpose4<<<dim3(32, 32, 4), tb, 0, stream>>>(
        Wq, Wk, Wv, Wo, flags,
        WT, WT + wsz / 2, WT + wsz, WoT);
    concat_bias<<<16, tb, 0, stream>>>(bq, bk, bv, bo, flags, bias);
    // fused QKV: N=3072, grid 24 col-tiles x 128 row-groups
    gemm_glds<u16><<<24 * 128, tb, 0, stream>>>(xb, WT, bias, qkv, NQKV);
    retention_mfma<<<dim3(N_CHUNKS, BATCH, N_HEADS), tb, 0, stream>>>(qkv, dec, xb);
    gemm_glds<float><<<8 * 128, tb, 0, stream>>>(xb, WoT, bias + 3072, out, D_MODEL);
}